// Round 9
// baseline (194.532 us; speedup 1.0000x reference)
//
#include <hip/hip_runtime.h>
#include <hip/hip_fp16.h>
#include <math.h>

#define NRAYS 16384
#define HID 64

typedef float    float4_ __attribute__((ext_vector_type(4)));
typedef _Float16 half8   __attribute__((ext_vector_type(8)));
typedef __fp16   fp16x2  __attribute__((ext_vector_type(2)));

__device__ __forceinline__ float clip1(float v){ return fminf(fmaxf(v,-1.f),1.f); }
__device__ __forceinline__ float softplusf_(float x){
  return fmaxf(x,0.f) + __logf(1.f + __expf(-fabsf(x)));
}
__device__ __forceinline__ float sigmoidf_(float x){
  return __fdividef(1.f, 1.f + __expf(-x));
}
__device__ __forceinline__ float h2f(unsigned short u){
  union { unsigned short s; __fp16 h; } cv; cv.s = u; return (float)cv.h;
}

// 1-inst HW pack: 2 floats -> 2 f16 (RTZ). a -> low16, b -> high16.
__device__ __forceinline__ unsigned int pkh(float a, float b){
  union { fp16x2 h; unsigned int u; } cv;
  cv.h = __builtin_amdgcn_cvt_pkrtz(a, b);
  return cv.u;
}
__device__ __forceinline__ unsigned long long pk64(float4_ a){
  return (unsigned long long)pkh(a[0],a[1]) | ((unsigned long long)pkh(a[2],a[3])<<32);
}
// packed relu on 2 f16 lanes in one VOP3P inst
__device__ __forceinline__ unsigned int relu_pk(unsigned int x){
  unsigned int y;
  __asm__("v_pk_max_f16 %0, %1, 0" : "=v"(y) : "v"(x));
  return y;
}

__device__ __forceinline__ void load_ray(const float* ro, const float* rd, int r,
    float& ox,float& oy,float& oz,float& dx,float& dy,float& dz){
  ox=ro[3*r]; oy=ro[3*r+1]; oz=ro[3*r+2];
  dx=rd[3*r]; dy=rd[3*r+1]; dz=rd[3*r+2];
  float inv = 1.f/sqrtf(dx*dx+dy*dy+dz*dz);
  dx*=inv; dy*=inv; dz*=inv;
}

__device__ __forceinline__ void aabb_nf(float ox,float oy,float oz,float dx,float dy,float dz,
    float& nears,float& fars){
  float dsx = (fabsf(dx)<1e-8f)?1e-8f:dx;
  float dsy = (fabsf(dy)<1e-8f)?1e-8f:dy;
  float dsz = (fabsf(dz)<1e-8f)?1e-8f:dz;
  float t1x=(-1.f-ox)/dsx, t2x=(1.f-ox)/dsx;
  float t1y=(-1.f-oy)/dsy, t2y=(1.f-oy)/dsy;
  float t1z=(-1.f-oz)/dsz, t2z=(1.f-oz)/dsz;
  float nr = fmaxf(fmaxf(fminf(t1x,t2x),fminf(t1y,t2y)),fminf(t1z,t2z));
  float fr = fminf(fminf(fmaxf(t1x,t2x),fmaxf(t1y,t2y)),fmaxf(t1z,t2z));
  fars  = fmaxf(fminf(fr,5.f),0.2f);
  nears = fminf(fmaxf(nr,0.2f),5.f);
}

// wave-level exclusive scan over per-lane chunk sums; no barriers.
__device__ __forceinline__ float wave_excl_chunk(float chunk, int lane, float& total){
  float incl = chunk;
  #pragma unroll
  for(int off=1; off<64; off<<=1){
    float n = __shfl_up(incl, off, 64);
    if (lane >= off) incl += n;
  }
  total = __shfl(incl, 63, 64);
  return incl - chunk;
}

// ---------------- weight prep: f16 A-fragments (transposed weights) ----------------
// A-frag: lane l holds A[m=l&15][k=(l>>4)*8+j]. 12 slots of 64 lanes x 8 halves:
// slots 0..3 : W1^T  (M-tile mt: m=h=mt*16+c):  A = W1[k][h], k>=3 -> 0
// slots 4..5 : W2^T  (K-step ks: k=h=ks*32+..): A = W2[h][od=c]
// slots 6..9 : Wc1^T (M-tile mt), PERMUTED k:   k=0 -> 0 row (od0=sigma unused);
//              k in 1..15 -> geo_{k-1} (Wc1 row 5+k); k in 16..21 -> pos/dir
//              (Wc1 row k-16); k>=22 -> 0
// slots 10..11: Wc2^T: A = (c<3)? Wc2[h][c] : 0
__global__ void prep_weights(const float* __restrict__ W1, const float* __restrict__ W2,
                             const float* __restrict__ Wc1, const float* __restrict__ Wc2,
                             unsigned short* __restrict__ wb){
  int idx = blockIdx.x*256 + threadIdx.x;
  if (idx >= 6144) return;
  int f = idx>>3, j = idx&7, lane = f&63, slot = f>>6, q = lane>>4, c = lane&15;
  int k = q*8+j;
  float v = 0.f;
  if (slot < 4){        if (k<3) v = W1[k*HID + slot*16 + c]; }
  else if (slot < 6){   int h=(slot-4)*32+k; v = W2[h*16 + c]; }
  else if (slot < 10){  int mt=slot-6;
                        int row = (k==0)? -1 : (k<16 ? 5+k : (k<22 ? k-16 : -1));
                        if (row>=0) v = Wc1[row*HID + mt*16 + c]; }
  else {                int h=(slot-10)*32+k; if (c<3) v = Wc2[h*3 + c]; }
  wb[idx] = __half_as_ushort(__float2half_rn(v));
}

// pack a layer-1 C-tile (4 h-rows, sample c) + packed relu -> one b64 into frag-major H
__device__ __forceinline__ void storeH(unsigned short* H, float4_ a, int t, int hbase){
  unsigned int lo = relu_pk(pkh(a[0],a[1]));
  unsigned int hi = relu_pk(pkh(a[2],a[3]));
  *(unsigned long long*)&H[hbase + t*256] =
      (unsigned long long)lo | ((unsigned long long)hi<<32);
}

// ====== fully fused NeRF: 1 WAVE per ray, 2 rays/block (128 thr), no barriers ======
// v10 = v4 (best measured 116.5us; phases = binary search, v9 histograms were
// neutral) + AFFINE FAST PATH for density L1:
// x(z) = o + d*z is affine-monotone per coord; if BOTH endpoint positions
// x(near), x(far) are inside [-1,1]^3 then clip is identity on the whole segment
// (coarse AND fine z all lie in [near,far]) and the L1 pre-activation is affine:
// h(z) = hb + z*hd with hb = W1^T o + b1, hd = W1^T d (per-ray constants, 32 f32
// regs, loaded once). Fast path (~90% of rays, wave-uniform branch since 1 wave
// = 1 ray) builds the L2 B-frags DIRECTLY in registers (16 fma + fmax + pkh per
// group), deleting per pairbody: 8 MFMAs, 8 storeH, 4 ds_read_b128, and the
// pack->MFMA->ds_write->lgkmcnt->ds_read critical chain. Slow path: v4 verbatim.
// Spill tripwire: VGPR ~110 expected; FETCH_SIZE >> 2MB => spilled, revert.
__global__ __launch_bounds__(128) void nerf_fused(
    const float* __restrict__ ro, const float* __restrict__ rd,
    const float* __restrict__ W1g, const float* __restrict__ b1,
    const float* __restrict__ b2,
    const float* __restrict__ bc1, const float* __restrict__ bc2,
    const unsigned short* __restrict__ wb, float* __restrict__ out)
{
  __shared__ __align__(16) unsigned short Hfrag[2][2][1024];     // 8 KB (scratch; hosts cdf/zM)
  __shared__ __align__(16) unsigned long long RGBS[2][256];      // 4 KB: (r,g,b,sigma) f16 LOGITS
  __shared__ __align__(16) float zBs[2][128];                    // 1 KB

  const int tid = threadIdx.x, lane = tid&63, wv = tid>>6;
  const int q = lane>>4, c = lane&15;
  const int r = blockIdx.x*2 + wv;

  float ox,oy,oz,dx,dy,dz;
  load_ray(ro,rd,r,ox,oy,oz,dx,dy,dz);
  float nears,fars; aabb_nf(ox,oy,oz,dx,dy,dz,nears,fars);
  const float step  = (fars-nears)*(1.f/127.f);
  const float sdist = (fars-nears)*(1.f/128.f);
  const bool asc = (nears <= fars);
  const unsigned int pk_dydz = pkh(dy,dz);   // ray-constant word for color input

  // ---- affine-L1 eligibility: endpoints of the segment inside the box =>
  //      clip is identity for every coarse/fine sample (monotone affine) ----
  bool fastL1;
  {
    float xn = fmaf(dx,nears,ox), yn = fmaf(dy,nears,oy), zn = fmaf(dz,nears,oz);
    float xf = fmaf(dx,fars,ox),  yf = fmaf(dy,fars,oy),  zf = fmaf(dz,fars,oz);
    float mx = fmaxf(fmaxf(fmaxf(fabsf(xn),fabsf(yn)),fabsf(zn)),
                     fmaxf(fmaxf(fabsf(xf),fabsf(yf)),fabsf(zf)));
    fastL1 = (mx <= 1.0f);                         // wave-uniform (ray-constant)
  }
  // per-lane affine L1 constants: rows q*8+j (j<8) and 32+q*8+j
  float hbA[8], hdA[8], hbB[8], hdB[8];
  {
    const int r0 = q*8;
    #pragma unroll
    for(int j=0;j<8;j++){
      int ra = r0 + j, rb = 32 + r0 + j;
      float wa0=W1g[ra], wa1=W1g[64+ra], wa2=W1g[128+ra];
      float wb0=W1g[rb], wb1=W1g[64+rb], wb2=W1g[128+rb];
      hbA[j] = ox*wa0 + oy*wa1 + oz*wa2 + b1[ra];
      hdA[j] = dx*wa0 + dy*wa1 + dz*wa2;
      hbB[j] = ox*wb0 + oy*wb1 + oz*wb2 + b1[rb];
      hdB[j] = dx*wb0 + dy*wb1 + dz*wb2;
    }
  }

  const half8* WF = (const half8*)wb;
  half8 aW1T[4], aW2T[2], aWc1T[4], aWc2T[2];
  #pragma unroll
  for(int t=0;t<4;t++){ aW1T[t] = WF[t*64+lane]; aWc1T[t] = WF[(6+t)*64+lane]; }
  #pragma unroll
  for(int k=0;k<2;k++){ aW2T[k] = WF[(4+k)*64+lane]; aWc2T[k] = WF[(10+k)*64+lane]; }
  float4_ b1v[4], bc1v[4];
  #pragma unroll
  for(int t=0;t<4;t++){
    b1v[t]  = *(const float4_*)&b1[t*16+q*4];
    bc1v[t] = *(const float4_*)&bc1[t*16+q*4];
  }
  const float4_ bTd = *(const float4_*)&b2[q*4];
  float4_ bTc = (float4_){0.f,0.f,0.f,0.f};
  if (q==0){ bTc[0]=bc2[0]; bTc[1]=bc2[1]; bTc[2]=bc2[2]; }

  unsigned short* H0 = &Hfrag[wv][0][0];
  unsigned short* H1 = &Hfrag[wv][1][0];
  unsigned long long* RGBSw = RGBS[wv];
  float* zBsw = zBs[wv];
  // cdf / merged-z overlay Hfrag[wv]: cdf lives (post-pass0 .. sampling), zM lives
  // (post-pass1 .. composite); Hfrag itself is scratch only inside MLP bodies.
  float* cdfw = (float*)&Hfrag[wv][0][0];
  float* zMw  = (float*)&Hfrag[wv][0][0];
  const int hbase  = (q>>1)*128 + c*8 + (q&1)*4;   // ushort index (H writer)
  const int lread  = lane*8;                        // ushort index (H reader)
  // bpermute source byte-addrs: writer lanes (2q, c) and (2q+1, c)
  const int ba0 = (q*32 + c)*4;
  const int ba1 = ba0 + 64;

  // build one L2 B-frag half8 from affine constants (relu fused; RTZ pack)
  auto mk8A = [&](float z)->half8 {
    half8 h;
    unsigned int* up = (unsigned int*)&h;
    #pragma unroll
    for(int j=0;j<4;j++)
      up[j] = pkh(fmaxf(fmaf(z,hdA[2*j],hbA[2*j]),0.f),
                  fmaxf(fmaf(z,hdA[2*j+1],hbA[2*j+1]),0.f));
    return h;
  };
  auto mk8B = [&](float z)->half8 {
    half8 h;
    unsigned int* up = (unsigned int*)&h;
    #pragma unroll
    for(int j=0;j<4;j++)
      up[j] = pkh(fmaxf(fmaf(z,hdB[2*j],hbB[2*j]),0.f),
                  fmaxf(fmaf(z,hdB[2*j+1],hbB[2*j+1]),0.f));
    return h;
  };

  // ---- one fused pair-iteration: density L1 (affine fast path or v4 MFMA path),
  //      L2, geo via bpermute, color L1->L2, raw logits -> RGBS. 32 samples. ----
  auto pairbody = [&](int p, int sbase, bool coarse){
    const int sidx0 = p*32 + c, sidx1 = p*32 + 16 + c;
    // sample z for this lane's column (c-dependent only; LDS read is broadcast)
    float z0u, z1u;
    if (coarse){ z0u = fmaf(step,(float)sidx0,nears); z1u = fmaf(step,(float)sidx1,nears); }
    else       { z0u = zBsw[sidx0];                   z1u = zBsw[sidx1]; }

    half8 bf0 = (half8)(_Float16)0, bf1 = (half8)(_Float16)0;
    unsigned int c0a=0u,c0b=0u,c1a=0u,c1b=0u;     // color pos words (q==2)
    if ((q&1)==0){                                 // q==0 (density pack, slow) & q==2 (color pack)
      float x0 = clip1(fmaf(dx,z0u,ox)), y0 = clip1(fmaf(dy,z0u,oy)), g0 = clip1(fmaf(dz,z0u,oz));
      float x1 = clip1(fmaf(dx,z1u,ox)), y1 = clip1(fmaf(dy,z1u,oy)), g1 = clip1(fmaf(dz,z1u,oz));
      if (q==0){
        unsigned int* u0p = (unsigned int*)&bf0;
        u0p[0] = pkh(x0,y0); u0p[1] = pkh(g0,0.f);
        unsigned int* u1p = (unsigned int*)&bf1;
        u1p[0] = pkh(x1,y1); u1p[1] = pkh(g1,0.f);
      } else {
        c0a = pkh(x0,y0); c0b = pkh(g0,dx);
        c1a = pkh(x1,y1); c1b = pkh(g1,dx);
      }
    }
    half8 h00, h01, h10, h11;
    if (fastL1){
      // affine L1: B-frags directly in registers; no MFMA, no LDS roundtrip
      h00 = mk8A(z0u); h01 = mk8B(z0u);
      h10 = mk8A(z1u); h11 = mk8B(z1u);
    } else {
      // v4 path: density layer 1 via MFMA + H roundtrip
      #pragma unroll
      for(int t=0;t<4;t++){
        float4_ a0 = __builtin_amdgcn_mfma_f32_16x16x32_f16(aW1T[t], bf0, b1v[t], 0,0,0);
        float4_ a1 = __builtin_amdgcn_mfma_f32_16x16x32_f16(aW1T[t], bf1, b1v[t], 0,0,0);
        storeH(H0, a0, t, hbase);
        storeH(H1, a1, t, hbase);
      }
      h00 = *(const half8*)&H0[lread];
      h01 = *(const half8*)&H0[512 + lread];
      h10 = *(const half8*)&H1[lread];
      h11 = *(const half8*)&H1[512 + lread];
    }
    // density layer 2 -> sigma logit + geo (C-frag: lane holds rows q*4..q*4+3, col c)
    float4_ o0 = __builtin_amdgcn_mfma_f32_16x16x32_f16(aW2T[0], h00, bTd, 0,0,0);
    o0 = __builtin_amdgcn_mfma_f32_16x16x32_f16(aW2T[1], h01, o0, 0,0,0);
    float4_ o1 = __builtin_amdgcn_mfma_f32_16x16x32_f16(aW2T[0], h10, bTd, 0,0,0);
    o1 = __builtin_amdgcn_mfma_f32_16x16x32_f16(aW2T[1], h11, o1, 0,0,0);
    // geo C-frag -> color B-frag via bpermute: target lane (q,c), q<2, takes
    // k=q*8+j from writer lanes (2q,c) [j0..3] and (2q+1,c) [j4..7].
    unsigned int pg0a = pkh(o0[0],o0[1]), pg0b = pkh(o0[2],o0[3]);
    unsigned int pg1a = pkh(o1[0],o1[1]), pg1b = pkh(o1[2],o1[3]);
    half8 bcf0, bcf1;
    {
      unsigned int* u0p = (unsigned int*)&bcf0;
      unsigned int* u1p = (unsigned int*)&bcf1;
      u0p[0] = (unsigned int)__builtin_amdgcn_ds_bpermute(ba0, (int)pg0a);
      u0p[1] = (unsigned int)__builtin_amdgcn_ds_bpermute(ba0, (int)pg0b);
      u0p[2] = (unsigned int)__builtin_amdgcn_ds_bpermute(ba1, (int)pg0a);
      u0p[3] = (unsigned int)__builtin_amdgcn_ds_bpermute(ba1, (int)pg0b);
      u1p[0] = (unsigned int)__builtin_amdgcn_ds_bpermute(ba0, (int)pg1a);
      u1p[1] = (unsigned int)__builtin_amdgcn_ds_bpermute(ba0, (int)pg1b);
      u1p[2] = (unsigned int)__builtin_amdgcn_ds_bpermute(ba1, (int)pg1a);
      u1p[3] = (unsigned int)__builtin_amdgcn_ds_bpermute(ba1, (int)pg1b);
      if (q == 2){                                  // k16..21 = pos/dir (k22,23 weights = 0)
        u0p[0] = c0a; u0p[1] = c0b; u0p[2] = pk_dydz; u0p[3] = 0u;
        u1p[0] = c1a; u1p[1] = c1b; u1p[2] = pk_dydz; u1p[3] = 0u;
      }
      // q==3 lanes: bperm garbage is finite f16; k24..31 weights are 0 -> harmless.
    }
    // color layer 1 (H roundtrip in both paths; color input is not affine)
    #pragma unroll
    for(int t=0;t<4;t++){
      float4_ a0 = __builtin_amdgcn_mfma_f32_16x16x32_f16(aWc1T[t], bcf0, bc1v[t], 0,0,0);
      float4_ a1 = __builtin_amdgcn_mfma_f32_16x16x32_f16(aWc1T[t], bcf1, bc1v[t], 0,0,0);
      storeH(H0, a0, t, hbase);
      storeH(H1, a1, t, hbase);
    }
    h00 = *(const half8*)&H0[lread];
    h01 = *(const half8*)&H0[512 + lread];
    h10 = *(const half8*)&H1[lread];
    h11 = *(const half8*)&H1[512 + lread];
    float4_ oc0 = __builtin_amdgcn_mfma_f32_16x16x32_f16(aWc2T[0], h00, bTc, 0,0,0);
    oc0 = __builtin_amdgcn_mfma_f32_16x16x32_f16(aWc2T[1], h01, oc0, 0,0,0);
    float4_ oc1 = __builtin_amdgcn_mfma_f32_16x16x32_f16(aWc2T[0], h10, bTc, 0,0,0);
    oc1 = __builtin_amdgcn_mfma_f32_16x16x32_f16(aWc2T[1], h11, oc1, 0,0,0);
    if (q==0){   // store RAW logits; softplus/sigmoid deferred to full-wave phases
      RGBSw[sbase+sidx0] = pk64((float4_){oc0[0], oc0[1], oc0[2], o0[0]});
      RGBSw[sbase+sidx1] = pk64((float4_){oc1[0], oc1[1], oc1[2], o1[0]});
    }
  };

  // ---------- pass 0: coarse density+color (4 pair-iterations) ----------
  #pragma unroll
  for(int p=0;p<4;p++) pairbody(p, 0, true);

  // ---------- pdf: wave-local exp-space scan + cdf (2 elems/lane) ----------
  {
    unsigned long long e0u = RGBSw[2*lane];
    unsigned long long e1u = RGBSw[2*lane+1];
    float s0 = softplusf_(h2f((unsigned short)(e0u>>48)));
    float s1 = softplusf_(h2f((unsigned short)(e1u>>48)));
    float d0 = (2*lane   < 127) ? step*s0 : 0.f;
    float d1 = (2*lane+1 < 127) ? step*s1 : 0.f;
    float tot;
    float e0 = wave_excl_chunk(d0+d1, lane, tot);
    float w0 = (1.f-__expf(-d0))*__expf(-e0);
    float w1 = (1.f-__expf(-d1))*__expf(-(e0+d0));
    float ww0 = (lane>=1 && 2*lane<127) ? w0+1e-5f : 0.f;   // i=0 excluded
    float ww1 = (2*lane+1 < 127) ? w1+1e-5f : 0.f;
    float wsum;
    float ce0 = wave_excl_chunk(ww0+ww1, lane, wsum);
    float inv = __fdividef(1.f, wsum);
    cdfw[2*lane]   = (ce0+ww0)*inv;
    cdfw[2*lane+1] = (ce0+ww0+ww1)*inv;                     // cdf[127] written, never read
  }

  // ---------- inverse-CDF sampling (2 fine samples/lane), stored z-sorted ----------
  {
    const float u0c = 0.5f/128.f;
    const float du = (1.f - 1.f/128.f)/127.f;
    #pragma unroll
    for(int j=0;j<2;j++){
      int k = lane + j*64;
      float u = fmaf(du,(float)k,u0c);
      int lo=0, hi=127;
      while(lo<hi){ int m=(lo+hi)>>1; if (cdfw[m] <= u) lo=m+1; else hi=m; }
      int below = max(lo-1,0), above = min(lo,126);
      float c0 = cdfw[below], c1 = cdfw[above];
      float bb0 = nears + step*((float)below + 0.5f);
      float bb1 = nears + step*((float)above + 0.5f);
      float den = c1 - c0; if (den < 1e-5f) den = 1.f;
      float zf = bb0 + (u - c0)/den*(bb1 - bb0);
      zBsw[asc ? k : 127-k] = zf;
    }
  }

  // ---------- pass 1: fine density+color, processed in z-sorted order ----------
  #pragma unroll
  for(int p=0;p<4;p++) pairbody(p, 128, false);

  // ---------- merge: coarse ranks via LDS binary search over fine list;
  //            fine ranks vs UNIFORM coarse grid in closed form + exact fixup ----------
  #pragma unroll
  for(int j=0;j<2;j++){
    int sA = lane + j*64;
    int i = asc ? sA : 127-sA;
    float myz = fmaf(step,(float)i,nears);
    int lo=0, hi=128;
    while(lo<hi){ int m=(lo+hi)>>1; if (zBsw[m] < myz) lo=m+1; else hi=m; }
    int pos = sA + lo;
    zMw[pos] = __uint_as_float((__float_as_uint(myz) & ~255u) | (unsigned)i);
  }
  const float inv_step = (step != 0.f) ? __fdividef(1.f, step) : 0.f;
  #pragma unroll
  for(int j=0;j<2;j++){
    int k = lane + j*64;
    float myz = zBsw[k];
    // A(m) = fmaf(step,(float)(asc?m:127-m),nears) is ascending in m; count A(m)<=myz.
    float tt = (myz - nears)*inv_step;
    float mr = (step == 0.f) ? 200.f : (asc ? tt : 127.f - tt);
    mr = fminf(fmaxf(mr, -2.f), 130.f);            // NaN-safe clamp (fmin/fmax drop NaN)
    int lo = (int)floorf(mr) + 1;
    lo = min(max(lo,0),128);
    while (lo<128 && fmaf(step,(float)(asc?lo:127-lo),nears) <= myz) lo++;
    while (lo>0  && fmaf(step,(float)(asc?(lo-1):(128-lo)),nears) >  myz) lo--;
    int pos = k + lo;
    zMw[pos] = __uint_as_float((__float_as_uint(myz) & ~255u) | (unsigned)(128+k));
  }

  // ---------- composite + accumulate: 4 merged samples/lane; softplus/sigmoid
  //            applied here at full lane utilization ----------
  float accR=0.f, accG=0.f, accB=0.f, accW=0.f;
  {
    float4_ z4 = *(const float4_*)&zMw[4*lane];
    float z5 = zMw[4*lane+4];                      // lane63 reads pad (unused via select)
    int oi0 = (int)(__float_as_uint(z4[0]) & 255u);
    int oi1 = (int)(__float_as_uint(z4[1]) & 255u);
    int oi2 = (int)(__float_as_uint(z4[2]) & 255u);
    int oi3 = (int)(__float_as_uint(z4[3]) & 255u);
    unsigned long long p0 = RGBSw[oi0];
    unsigned long long p1 = RGBSw[oi1];
    unsigned long long p2 = RGBSw[oi2];
    unsigned long long p3 = RGBSw[oi3];
    float sg0 = softplusf_(h2f((unsigned short)(p0>>48)));
    float sg1 = softplusf_(h2f((unsigned short)(p1>>48)));
    float sg2 = softplusf_(h2f((unsigned short)(p2>>48)));
    float sg3 = softplusf_(h2f((unsigned short)(p3>>48)));
    float d0 = (z4[1]-z4[0])*sg0;
    float d1 = (z4[2]-z4[1])*sg1;
    float d2 = (z4[3]-z4[2])*sg2;
    float dl = (lane==63) ? sdist : (z5 - z4[3]);
    float d3 = dl*sg3;
    float tot;
    float S = wave_excl_chunk(d0+d1+d2+d3, lane, tot);
    float4_ w4;
    w4[0] = (1.f-__expf(-d0))*__expf(-S); S += d0;
    w4[1] = (1.f-__expf(-d1))*__expf(-S); S += d1;
    w4[2] = (1.f-__expf(-d2))*__expf(-S); S += d2;
    w4[3] = (1.f-__expf(-d3))*__expf(-S);
    accW = w4[0]+w4[1]+w4[2]+w4[3];                // weights_sum is unmasked (ref)
    if (w4[0] > 1e-4f){
      accR = fmaf(w4[0], sigmoidf_(h2f((unsigned short) p0      )), accR);
      accG = fmaf(w4[0], sigmoidf_(h2f((unsigned short)(p0>>16))), accG);
      accB = fmaf(w4[0], sigmoidf_(h2f((unsigned short)(p0>>32))), accB);
    }
    if (w4[1] > 1e-4f){
      accR = fmaf(w4[1], sigmoidf_(h2f((unsigned short) p1      )), accR);
      accG = fmaf(w4[1], sigmoidf_(h2f((unsigned short)(p1>>16))), accG);
      accB = fmaf(w4[1], sigmoidf_(h2f((unsigned short)(p1>>32))), accB);
    }
    if (w4[2] > 1e-4f){
      accR = fmaf(w4[2], sigmoidf_(h2f((unsigned short) p2      )), accR);
      accG = fmaf(w4[2], sigmoidf_(h2f((unsigned short)(p2>>16))), accG);
      accB = fmaf(w4[2], sigmoidf_(h2f((unsigned short)(p2>>32))), accB);
    }
    if (w4[3] > 1e-4f){
      accR = fmaf(w4[3], sigmoidf_(h2f((unsigned short) p3      )), accR);
      accG = fmaf(w4[3], sigmoidf_(h2f((unsigned short)(p3>>16))), accG);
      accB = fmaf(w4[3], sigmoidf_(h2f((unsigned short)(p3>>32))), accB);
    }
  }

  // ---------- wave reduce + output ----------
  #pragma unroll
  for(int off=32; off; off>>=1){
    accR += __shfl_down(accR, off, 64);
    accG += __shfl_down(accG, off, 64);
    accB += __shfl_down(accB, off, 64);
    accW += __shfl_down(accW, off, 64);
  }
  if (lane == 0){
    float bg = 1.f - accW;
    out[r*3+0] = accR + bg;
    out[r*3+1] = accG + bg;
    out[r*3+2] = accB + bg;
  }
}

extern "C" void kernel_launch(void* const* d_in, const int* in_sizes, int n_in,
                              void* d_out, int out_size, void* d_ws, size_t ws_size,
                              hipStream_t stream) {
  const float* ro  = (const float*)d_in[0];
  const float* rd  = (const float*)d_in[1];
  const float* W1  = (const float*)d_in[2];
  const float* b1  = (const float*)d_in[3];
  const float* W2  = (const float*)d_in[4];
  const float* b2  = (const float*)d_in[5];
  const float* Wc1 = (const float*)d_in[6];
  const float* bc1 = (const float*)d_in[7];
  const float* Wc2 = (const float*)d_in[8];
  const float* bc2 = (const float*)d_in[9];
  float* out = (float*)d_out;

  unsigned short* wb = (unsigned short*)d_ws;   // 6144 f16 fragment words

  prep_weights<<<dim3(24), dim3(256), 0, stream>>>(W1, W2, Wc1, Wc2, wb);
  nerf_fused<<<dim3(NRAYS/2), dim3(128), 0, stream>>>(
      ro, rd, W1, b1, b2, bc1, bc2, wb, out);
}

// Round 10
// 171.972 us; speedup vs baseline: 1.1312x; 1.1312x over previous
//
#include <hip/hip_runtime.h>
#include <hip/hip_fp16.h>
#include <math.h>

#define NRAYS 16384
#define HID 64

typedef float    float4_ __attribute__((ext_vector_type(4)));
typedef _Float16 half8   __attribute__((ext_vector_type(8)));
typedef __fp16   fp16x2  __attribute__((ext_vector_type(2)));

__device__ __forceinline__ float clip1(float v){ return fminf(fmaxf(v,-1.f),1.f); }
__device__ __forceinline__ float softplusf_(float x){
  return fmaxf(x,0.f) + __logf(1.f + __expf(-fabsf(x)));
}
__device__ __forceinline__ float sigmoidf_(float x){
  return __fdividef(1.f, 1.f + __expf(-x));
}
__device__ __forceinline__ float h2f(unsigned short u){
  union { unsigned short s; __fp16 h; } cv; cv.s = u; return (float)cv.h;
}

// 1-inst HW pack: 2 floats -> 2 f16 (RTZ). a -> low16, b -> high16.
__device__ __forceinline__ unsigned int pkh(float a, float b){
  union { fp16x2 h; unsigned int u; } cv;
  cv.h = __builtin_amdgcn_cvt_pkrtz(a, b);
  return cv.u;
}
__device__ __forceinline__ unsigned long long pk64(float4_ a){
  return (unsigned long long)pkh(a[0],a[1]) | ((unsigned long long)pkh(a[2],a[3])<<32);
}
// packed relu on 2 f16 lanes in one VOP3P inst
__device__ __forceinline__ unsigned int relu_pk(unsigned int x){
  unsigned int y;
  __asm__("v_pk_max_f16 %0, %1, 0" : "=v"(y) : "v"(x));
  return y;
}

__device__ __forceinline__ void load_ray(const float* ro, const float* rd, int r,
    float& ox,float& oy,float& oz,float& dx,float& dy,float& dz){
  ox=ro[3*r]; oy=ro[3*r+1]; oz=ro[3*r+2];
  dx=rd[3*r]; dy=rd[3*r+1]; dz=rd[3*r+2];
  float inv = 1.f/sqrtf(dx*dx+dy*dy+dz*dz);
  dx*=inv; dy*=inv; dz*=inv;
}

__device__ __forceinline__ void aabb_nf(float ox,float oy,float oz,float dx,float dy,float dz,
    float& nears,float& fars){
  float dsx = (fabsf(dx)<1e-8f)?1e-8f:dx;
  float dsy = (fabsf(dy)<1e-8f)?1e-8f:dy;
  float dsz = (fabsf(dz)<1e-8f)?1e-8f:dz;
  float t1x=(-1.f-ox)/dsx, t2x=(1.f-ox)/dsx;
  float t1y=(-1.f-oy)/dsy, t2y=(1.f-oy)/dsy;
  float t1z=(-1.f-oz)/dsz, t2z=(1.f-oz)/dsz;
  float nr = fmaxf(fmaxf(fminf(t1x,t2x),fminf(t1y,t2y)),fminf(t1z,t2z));
  float fr = fminf(fminf(fmaxf(t1x,t2x),fmaxf(t1y,t2y)),fmaxf(t1z,t2z));
  fars  = fmaxf(fminf(fr,5.f),0.2f);
  nears = fminf(fmaxf(nr,0.2f),5.f);
}

// wave-level exclusive scan over per-lane chunk sums; no barriers.
__device__ __forceinline__ float wave_excl_chunk(float chunk, int lane, float& total){
  float incl = chunk;
  #pragma unroll
  for(int off=1; off<64; off<<=1){
    float n = __shfl_up(incl, off, 64);
    if (lane >= off) incl += n;
  }
  total = __shfl(incl, 63, 64);
  return incl - chunk;
}

// ---------------- weight prep: f16 A-fragments (transposed weights) ----------------
// A-frag: lane l holds A[m=l&15][k=(l>>4)*8+j]. 12 slots of 64 lanes x 8 halves:
// slots 0..3 : W1^T  (M-tile mt: m=h=mt*16+c):  A = W1[k][h], k>=3 -> 0
// slots 4..5 : W2^T  (K-step ks: k=h=ks*32+..): A = W2[h][od=c]
// slots 6..9 : Wc1^T (M-tile mt), PERMUTED k:   k=0 -> 0 row (od0=sigma unused);
//              k in 1..15 -> geo_{k-1} (Wc1 row 5+k); k in 16..21 -> pos/dir
//              (Wc1 row k-16); k>=22 -> 0
// slots 10..11: Wc2^T: A = (c<3)? Wc2[h][c] : 0
__global__ void prep_weights(const float* __restrict__ W1, const float* __restrict__ W2,
                             const float* __restrict__ Wc1, const float* __restrict__ Wc2,
                             unsigned short* __restrict__ wb){
  int idx = blockIdx.x*256 + threadIdx.x;
  if (idx >= 6144) return;
  int f = idx>>3, j = idx&7, lane = f&63, slot = f>>6, q = lane>>4, c = lane&15;
  int k = q*8+j;
  float v = 0.f;
  if (slot < 4){        if (k<3) v = W1[k*HID + slot*16 + c]; }
  else if (slot < 6){   int h=(slot-4)*32+k; v = W2[h*16 + c]; }
  else if (slot < 10){  int mt=slot-6;
                        int row = (k==0)? -1 : (k<16 ? 5+k : (k<22 ? k-16 : -1));
                        if (row>=0) v = Wc1[row*HID + mt*16 + c]; }
  else {                int h=(slot-10)*32+k; if (c<3) v = Wc2[h*3 + c]; }
  wb[idx] = __half_as_ushort(__float2half_rn(v));
}

// pack a layer-1 C-tile (4 h-rows, sample c) + packed relu -> one b64 into frag-major H
__device__ __forceinline__ void storeH(unsigned short* H, float4_ a, int t, int hbase){
  unsigned int lo = relu_pk(pkh(a[0],a[1]));
  unsigned int hi = relu_pk(pkh(a[2],a[3]));
  *(unsigned long long*)&H[hbase + t*256] =
      (unsigned long long)lo | ((unsigned long long)hi<<32);
}

// ====== fully fused NeRF: 1 WAVE per ray, 2 rays/block (128 thr), no barriers ======
// v11 = v4 EXACT (best measured 116.5us) + s_setprio(1) around the pairbody
// compute region. Ablation ledger: 1-chain(136)/4-chain(144)/4-share-2(138)/
// histogram-phases(120)/affine-L1(137) all lost to v4's 2-chain + binary-search
// structure -> v4 is the local optimum for WHAT executes. setprio acts only on
// issue ARBITRATION: independent 1-wave blocks at different phases (exactly the
// m191 attn structure, +4-7%) -> compute-phase waves win slots over waves in
// scan/search phases. Zero reg/LDS/correctness cost.
__global__ __launch_bounds__(128) void nerf_fused(
    const float* __restrict__ ro, const float* __restrict__ rd,
    const float* __restrict__ b1, const float* __restrict__ b2,
    const float* __restrict__ bc1, const float* __restrict__ bc2,
    const unsigned short* __restrict__ wb, float* __restrict__ out)
{
  __shared__ __align__(16) unsigned short Hfrag[2][2][1024];     // 8 KB (scratch; hosts cdf/zM)
  __shared__ __align__(16) unsigned long long RGBS[2][256];      // 4 KB: (r,g,b,sigma) f16 LOGITS
  __shared__ __align__(16) float zBs[2][128];                    // 1 KB

  const int tid = threadIdx.x, lane = tid&63, wv = tid>>6;
  const int q = lane>>4, c = lane&15;
  const int r = blockIdx.x*2 + wv;

  float ox,oy,oz,dx,dy,dz;
  load_ray(ro,rd,r,ox,oy,oz,dx,dy,dz);
  float nears,fars; aabb_nf(ox,oy,oz,dx,dy,dz,nears,fars);
  const float step  = (fars-nears)*(1.f/127.f);
  const float sdist = (fars-nears)*(1.f/128.f);
  const bool asc = (nears <= fars);
  const unsigned int pk_dydz = pkh(dy,dz);   // ray-constant word for color input

  const half8* WF = (const half8*)wb;
  half8 aW1T[4], aW2T[2], aWc1T[4], aWc2T[2];
  #pragma unroll
  for(int t=0;t<4;t++){ aW1T[t] = WF[t*64+lane]; aWc1T[t] = WF[(6+t)*64+lane]; }
  #pragma unroll
  for(int k=0;k<2;k++){ aW2T[k] = WF[(4+k)*64+lane]; aWc2T[k] = WF[(10+k)*64+lane]; }
  float4_ b1v[4], bc1v[4];
  #pragma unroll
  for(int t=0;t<4;t++){
    b1v[t]  = *(const float4_*)&b1[t*16+q*4];
    bc1v[t] = *(const float4_*)&bc1[t*16+q*4];
  }
  const float4_ bTd = *(const float4_*)&b2[q*4];
  float4_ bTc = (float4_){0.f,0.f,0.f,0.f};
  if (q==0){ bTc[0]=bc2[0]; bTc[1]=bc2[1]; bTc[2]=bc2[2]; }

  unsigned short* H0 = &Hfrag[wv][0][0];
  unsigned short* H1 = &Hfrag[wv][1][0];
  unsigned long long* RGBSw = RGBS[wv];
  float* zBsw = zBs[wv];
  // cdf / merged-z overlay Hfrag[wv]: cdf lives (post-pass0 .. sampling), zM lives
  // (post-pass1 .. composite); Hfrag itself is scratch only inside pairbodies.
  float* cdfw = (float*)&Hfrag[wv][0][0];
  float* zMw  = (float*)&Hfrag[wv][0][0];
  const int hbase  = (q>>1)*128 + c*8 + (q&1)*4;   // ushort index (H writer)
  const int lread  = lane*8;                        // ushort index (H reader)
  // bpermute source byte-addrs: writer lanes (2q, c) and (2q+1, c)
  const int ba0 = (q*32 + c)*4;
  const int ba1 = ba0 + 64;

  // ---- one fused pair-iteration: density L1->L2, geo moved to color B-frag via
  //      bpermute, color L1->L2, raw (r,g,b,sigma) logits packed into RGBS. ----
  auto pairbody = [&](int p, int sbase, bool coarse){
    const int sidx0 = p*32 + c, sidx1 = p*32 + 16 + c;
    half8 bf0 = (half8)(_Float16)0, bf1 = (half8)(_Float16)0;
    unsigned int c0a=0u,c0b=0u,c1a=0u,c1b=0u;     // color pos words (q==2)
    if ((q&1)==0){                                 // q==0 (density pack) & q==2 (color pack)
      float z0 = coarse ? fmaf(step,(float)sidx0,nears) : zBsw[sidx0];
      float z1 = coarse ? fmaf(step,(float)sidx1,nears) : zBsw[sidx1];
      float x0 = clip1(fmaf(dx,z0,ox)), y0 = clip1(fmaf(dy,z0,oy)), g0 = clip1(fmaf(dz,z0,oz));
      float x1 = clip1(fmaf(dx,z1,ox)), y1 = clip1(fmaf(dy,z1,oy)), g1 = clip1(fmaf(dz,z1,oz));
      if (q==0){
        unsigned int* u0p = (unsigned int*)&bf0;
        u0p[0] = pkh(x0,y0); u0p[1] = pkh(g0,0.f);
        unsigned int* u1p = (unsigned int*)&bf1;
        u1p[0] = pkh(x1,y1); u1p[1] = pkh(g1,0.f);
      } else {
        c0a = pkh(x0,y0); c0b = pkh(g0,dx);
        c1a = pkh(x1,y1); c1b = pkh(g1,dx);
      }
    }
    // raise priority for the MFMA/pack compute region (runtime arbitration hint;
    // helps when co-resident waves are in scan/search phases — m191 structure)
    __builtin_amdgcn_s_setprio(1);
    // density layer 1
    #pragma unroll
    for(int t=0;t<4;t++){
      float4_ a0 = __builtin_amdgcn_mfma_f32_16x16x32_f16(aW1T[t], bf0, b1v[t], 0,0,0);
      float4_ a1 = __builtin_amdgcn_mfma_f32_16x16x32_f16(aW1T[t], bf1, b1v[t], 0,0,0);
      storeH(H0, a0, t, hbase);
      storeH(H1, a1, t, hbase);
    }
    half8 h00 = *(const half8*)&H0[lread];
    half8 h01 = *(const half8*)&H0[512 + lread];
    half8 h10 = *(const half8*)&H1[lread];
    half8 h11 = *(const half8*)&H1[512 + lread];
    // density layer 2 -> sigma logit + geo (C-frag: lane holds rows q*4..q*4+3, col c)
    float4_ o0 = __builtin_amdgcn_mfma_f32_16x16x32_f16(aW2T[0], h00, bTd, 0,0,0);
    o0 = __builtin_amdgcn_mfma_f32_16x16x32_f16(aW2T[1], h01, o0, 0,0,0);
    float4_ o1 = __builtin_amdgcn_mfma_f32_16x16x32_f16(aW2T[0], h10, bTd, 0,0,0);
    o1 = __builtin_amdgcn_mfma_f32_16x16x32_f16(aW2T[1], h11, o1, 0,0,0);
    // geo C-frag -> color B-frag via bpermute: target lane (q,c), q<2, takes
    // k=q*8+j from writer lanes (2q,c) [j0..3] and (2q+1,c) [j4..7].
    unsigned int pg0a = pkh(o0[0],o0[1]), pg0b = pkh(o0[2],o0[3]);
    unsigned int pg1a = pkh(o1[0],o1[1]), pg1b = pkh(o1[2],o1[3]);
    half8 bcf0, bcf1;
    {
      unsigned int* u0p = (unsigned int*)&bcf0;
      unsigned int* u1p = (unsigned int*)&bcf1;
      u0p[0] = (unsigned int)__builtin_amdgcn_ds_bpermute(ba0, (int)pg0a);
      u0p[1] = (unsigned int)__builtin_amdgcn_ds_bpermute(ba0, (int)pg0b);
      u0p[2] = (unsigned int)__builtin_amdgcn_ds_bpermute(ba1, (int)pg0a);
      u0p[3] = (unsigned int)__builtin_amdgcn_ds_bpermute(ba1, (int)pg0b);
      u1p[0] = (unsigned int)__builtin_amdgcn_ds_bpermute(ba0, (int)pg1a);
      u1p[1] = (unsigned int)__builtin_amdgcn_ds_bpermute(ba0, (int)pg1b);
      u1p[2] = (unsigned int)__builtin_amdgcn_ds_bpermute(ba1, (int)pg1a);
      u1p[3] = (unsigned int)__builtin_amdgcn_ds_bpermute(ba1, (int)pg1b);
      if (q == 2){                                  // k16..21 = pos/dir (k22,23 weights = 0)
        u0p[0] = c0a; u0p[1] = c0b; u0p[2] = pk_dydz; u0p[3] = 0u;
        u1p[0] = c1a; u1p[1] = c1b; u1p[2] = pk_dydz; u1p[3] = 0u;
      }
      // q==3 lanes: bperm garbage is finite f16; k24..31 weights are 0 -> harmless.
    }
    // color layer 1
    #pragma unroll
    for(int t=0;t<4;t++){
      float4_ a0 = __builtin_amdgcn_mfma_f32_16x16x32_f16(aWc1T[t], bcf0, bc1v[t], 0,0,0);
      float4_ a1 = __builtin_amdgcn_mfma_f32_16x16x32_f16(aWc1T[t], bcf1, bc1v[t], 0,0,0);
      storeH(H0, a0, t, hbase);
      storeH(H1, a1, t, hbase);
    }
    h00 = *(const half8*)&H0[lread];
    h01 = *(const half8*)&H0[512 + lread];
    h10 = *(const half8*)&H1[lread];
    h11 = *(const half8*)&H1[512 + lread];
    float4_ oc0 = __builtin_amdgcn_mfma_f32_16x16x32_f16(aWc2T[0], h00, bTc, 0,0,0);
    oc0 = __builtin_amdgcn_mfma_f32_16x16x32_f16(aWc2T[1], h01, oc0, 0,0,0);
    float4_ oc1 = __builtin_amdgcn_mfma_f32_16x16x32_f16(aWc2T[0], h10, bTc, 0,0,0);
    oc1 = __builtin_amdgcn_mfma_f32_16x16x32_f16(aWc2T[1], h11, oc1, 0,0,0);
    __builtin_amdgcn_s_setprio(0);
    if (q==0){   // store RAW logits; softplus/sigmoid deferred to full-wave phases
      RGBSw[sbase+sidx0] = pk64((float4_){oc0[0], oc0[1], oc0[2], o0[0]});
      RGBSw[sbase+sidx1] = pk64((float4_){oc1[0], oc1[1], oc1[2], o1[0]});
    }
  };

  // ---------- pass 0: coarse density+color (4 pair-iterations) ----------
  #pragma unroll
  for(int p=0;p<4;p++) pairbody(p, 0, true);

  // ---------- pdf: wave-local exp-space scan + cdf (2 elems/lane) ----------
  {
    unsigned long long e0u = RGBSw[2*lane];
    unsigned long long e1u = RGBSw[2*lane+1];
    float s0 = softplusf_(h2f((unsigned short)(e0u>>48)));
    float s1 = softplusf_(h2f((unsigned short)(e1u>>48)));
    float d0 = (2*lane   < 127) ? step*s0 : 0.f;
    float d1 = (2*lane+1 < 127) ? step*s1 : 0.f;
    float tot;
    float e0 = wave_excl_chunk(d0+d1, lane, tot);
    float w0 = (1.f-__expf(-d0))*__expf(-e0);
    float w1 = (1.f-__expf(-d1))*__expf(-(e0+d0));
    float ww0 = (lane>=1 && 2*lane<127) ? w0+1e-5f : 0.f;   // i=0 excluded
    float ww1 = (2*lane+1 < 127) ? w1+1e-5f : 0.f;
    float wsum;
    float ce0 = wave_excl_chunk(ww0+ww1, lane, wsum);
    float inv = __fdividef(1.f, wsum);
    cdfw[2*lane]   = (ce0+ww0)*inv;
    cdfw[2*lane+1] = (ce0+ww0+ww1)*inv;                     // cdf[127] written, never read
  }

  // ---------- inverse-CDF sampling (2 fine samples/lane), stored z-sorted ----------
  {
    const float u0c = 0.5f/128.f;
    const float du = (1.f - 1.f/128.f)/127.f;
    #pragma unroll
    for(int j=0;j<2;j++){
      int k = lane + j*64;
      float u = fmaf(du,(float)k,u0c);
      int lo=0, hi=127;
      while(lo<hi){ int m=(lo+hi)>>1; if (cdfw[m] <= u) lo=m+1; else hi=m; }
      int below = max(lo-1,0), above = min(lo,126);
      float c0 = cdfw[below], c1 = cdfw[above];
      float bb0 = nears + step*((float)below + 0.5f);
      float bb1 = nears + step*((float)above + 0.5f);
      float den = c1 - c0; if (den < 1e-5f) den = 1.f;
      float zf = bb0 + (u - c0)/den*(bb1 - bb0);
      zBsw[asc ? k : 127-k] = zf;
    }
  }

  // ---------- pass 1: fine density+color, processed in z-sorted order ----------
  #pragma unroll
  for(int p=0;p<4;p++) pairbody(p, 128, false);

  // ---------- merge: coarse ranks via LDS binary search over fine list;
  //            fine ranks vs UNIFORM coarse grid in closed form + exact fixup ----------
  #pragma unroll
  for(int j=0;j<2;j++){
    int sA = lane + j*64;
    int i = asc ? sA : 127-sA;
    float myz = fmaf(step,(float)i,nears);
    int lo=0, hi=128;
    while(lo<hi){ int m=(lo+hi)>>1; if (zBsw[m] < myz) lo=m+1; else hi=m; }
    int pos = sA + lo;
    zMw[pos] = __uint_as_float((__float_as_uint(myz) & ~255u) | (unsigned)i);
  }
  const float inv_step = (step != 0.f) ? __fdividef(1.f, step) : 0.f;
  #pragma unroll
  for(int j=0;j<2;j++){
    int k = lane + j*64;
    float myz = zBsw[k];
    // A(m) = fmaf(step,(float)(asc?m:127-m),nears) is ascending in m; count A(m)<=myz.
    float tt = (myz - nears)*inv_step;
    float mr = (step == 0.f) ? 200.f : (asc ? tt : 127.f - tt);
    mr = fminf(fmaxf(mr, -2.f), 130.f);            // NaN-safe clamp (fmin/fmax drop NaN)
    int lo = (int)floorf(mr) + 1;
    lo = min(max(lo,0),128);
    while (lo<128 && fmaf(step,(float)(asc?lo:127-lo),nears) <= myz) lo++;
    while (lo>0  && fmaf(step,(float)(asc?(lo-1):(128-lo)),nears) >  myz) lo--;
    int pos = k + lo;
    zMw[pos] = __uint_as_float((__float_as_uint(myz) & ~255u) | (unsigned)(128+k));
  }

  // ---------- composite + accumulate: 4 merged samples/lane; softplus/sigmoid
  //            applied here at full lane utilization ----------
  float accR=0.f, accG=0.f, accB=0.f, accW=0.f;
  {
    float4_ z4 = *(const float4_*)&zMw[4*lane];
    float z5 = zMw[4*lane+4];                      // lane63 reads pad (unused via select)
    int oi0 = (int)(__float_as_uint(z4[0]) & 255u);
    int oi1 = (int)(__float_as_uint(z4[1]) & 255u);
    int oi2 = (int)(__float_as_uint(z4[2]) & 255u);
    int oi3 = (int)(__float_as_uint(z4[3]) & 255u);
    unsigned long long p0 = RGBSw[oi0];
    unsigned long long p1 = RGBSw[oi1];
    unsigned long long p2 = RGBSw[oi2];
    unsigned long long p3 = RGBSw[oi3];
    float sg0 = softplusf_(h2f((unsigned short)(p0>>48)));
    float sg1 = softplusf_(h2f((unsigned short)(p1>>48)));
    float sg2 = softplusf_(h2f((unsigned short)(p2>>48)));
    float sg3 = softplusf_(h2f((unsigned short)(p3>>48)));
    float d0 = (z4[1]-z4[0])*sg0;
    float d1 = (z4[2]-z4[1])*sg1;
    float d2 = (z4[3]-z4[2])*sg2;
    float dl = (lane==63) ? sdist : (z5 - z4[3]);
    float d3 = dl*sg3;
    float tot;
    float S = wave_excl_chunk(d0+d1+d2+d3, lane, tot);
    float4_ w4;
    w4[0] = (1.f-__expf(-d0))*__expf(-S); S += d0;
    w4[1] = (1.f-__expf(-d1))*__expf(-S); S += d1;
    w4[2] = (1.f-__expf(-d2))*__expf(-S); S += d2;
    w4[3] = (1.f-__expf(-d3))*__expf(-S);
    accW = w4[0]+w4[1]+w4[2]+w4[3];                // weights_sum is unmasked (ref)
    if (w4[0] > 1e-4f){
      accR = fmaf(w4[0], sigmoidf_(h2f((unsigned short) p0      )), accR);
      accG = fmaf(w4[0], sigmoidf_(h2f((unsigned short)(p0>>16))), accG);
      accB = fmaf(w4[0], sigmoidf_(h2f((unsigned short)(p0>>32))), accB);
    }
    if (w4[1] > 1e-4f){
      accR = fmaf(w4[1], sigmoidf_(h2f((unsigned short) p1      )), accR);
      accG = fmaf(w4[1], sigmoidf_(h2f((unsigned short)(p1>>16))), accG);
      accB = fmaf(w4[1], sigmoidf_(h2f((unsigned short)(p1>>32))), accB);
    }
    if (w4[2] > 1e-4f){
      accR = fmaf(w4[2], sigmoidf_(h2f((unsigned short) p2      )), accR);
      accG = fmaf(w4[2], sigmoidf_(h2f((unsigned short)(p2>>16))), accG);
      accB = fmaf(w4[2], sigmoidf_(h2f((unsigned short)(p2>>32))), accB);
    }
    if (w4[3] > 1e-4f){
      accR = fmaf(w4[3], sigmoidf_(h2f((unsigned short) p3      )), accR);
      accG = fmaf(w4[3], sigmoidf_(h2f((unsigned short)(p3>>16))), accG);
      accB = fmaf(w4[3], sigmoidf_(h2f((unsigned short)(p3>>32))), accB);
    }
  }

  // ---------- wave reduce + output ----------
  #pragma unroll
  for(int off=32; off; off>>=1){
    accR += __shfl_down(accR, off, 64);
    accG += __shfl_down(accG, off, 64);
    accB += __shfl_down(accB, off, 64);
    accW += __shfl_down(accW, off, 64);
  }
  if (lane == 0){
    float bg = 1.f - accW;
    out[r*3+0] = accR + bg;
    out[r*3+1] = accG + bg;
    out[r*3+2] = accB + bg;
  }
}

extern "C" void kernel_launch(void* const* d_in, const int* in_sizes, int n_in,
                              void* d_out, int out_size, void* d_ws, size_t ws_size,
                              hipStream_t stream) {
  const float* ro  = (const float*)d_in[0];
  const float* rd  = (const float*)d_in[1];
  const float* W1  = (const float*)d_in[2];
  const float* b1  = (const float*)d_in[3];
  const float* W2  = (const float*)d_in[4];
  const float* b2  = (const float*)d_in[5];
  const float* Wc1 = (const float*)d_in[6];
  const float* bc1 = (const float*)d_in[7];
  const float* Wc2 = (const float*)d_in[8];
  const float* bc2 = (const float*)d_in[9];
  float* out = (float*)d_out;

  unsigned short* wb = (unsigned short*)d_ws;   // 6144 f16 fragment words

  prep_weights<<<dim3(24), dim3(256), 0, stream>>>(W1, W2, Wc1, Wc2, wb);
  nerf_fused<<<dim3(NRAYS/2), dim3(128), 0, stream>>>(
      ro, rd, b1, b2, bc1, bc2, wb, out);
}